// Round 6
// baseline (264.812 us; speedup 1.0000x reference)
//
#include <hip/hip_runtime.h>
#include <hip/hip_bf16.h>

#define NB   8
#define NS   5
#define TT   16
#define DD   2048
#define NROW 1024               // B*nq
#define NSROW 640               // supp rows
#define NQROW 16384             // query rows
#define TOTROW 17024
#define TILESH (TT * DD)        // 32768 shorts per packed 16x2048 tile
#define LAMI 10.0f
#define LAMF 0.1f

typedef __attribute__((ext_vector_type(8))) short  short8;
typedef __attribute__((ext_vector_type(4))) float  float4v;

// single-instruction packed f32x2 -> bf16x2 (RNE), lo = x
static __device__ __forceinline__ unsigned int cvtpk(float x, float y) {
    unsigned int r;
    asm("v_cvt_pk_bf16_f32 %0, %1, %2" : "=v"(r) : "v"(x), "v"(y));
    return r;
}

// lane i <- lane i-1 across the whole wave (lane 0 <- 0). 1 VALU op, no LDS.
static __device__ __forceinline__ float dpp_shr1(float x) {
    int r = __builtin_amdgcn_update_dpp(0, __builtin_bit_cast(int, x),
                                        0x138 /*wave_shr:1*/, 0xF, 0xF, true);
    return __builtin_bit_cast(float, r);
}

// ---- shared tail: DTW (12 groups of 18 lanes over 4 waves) + tam + CE ----
static __device__ __forceinline__ void
dtw_and_out(const float (*distS)[TT][TT], float* tamv, int tid, int blk,
            const int* __restrict__ ys, float* __restrict__ out)
{
    const int wave = tid >> 6, lane = tid & 63;
    {
        const int grp  = lane / 21;             // 3 => unused tail lanes
        const int g    = lane - grp * 21;       // 0..20 within group
        const int slot = wave * 3 + grp;        // s*2+dir
        float val = 0.f, vprev = 0.f;           // init ALL lanes (dpp sources)
        if (grp < 3 && slot < 10 && g <= 17) {
            const int s    = slot >> 1;
            const int dir  = slot & 1;
            const bool isb = (g == 1) | (g == 17);
            #pragma unroll
            for (int t = 1; t <= 32; ++t) {
                float left = dpp_shr1(val);
                float diag = dpp_shr1(vprev);
                int l = t - g;
                if (g >= 1 && l >= 0 && l <= 15) {
                    float d = 0.f;
                    if (g <= 16) d = dir ? distS[s][15 - l][16 - g] : distS[s][l][g - 1];
                    float nv;
                    if (l == 0) {
                        nv = left + d;
                    } else {
                        float am = -LAMI * diag, bm = -LAMI * left;
                        float mx = fmaxf(am, bm);
                        float s3 = 0.f;
                        if (isb) {
                            float cm = -LAMI * val;
                            float m3 = fmaxf(mx, cm);
                            s3 = __expf(cm - m3);
                            mx = m3;
                        }
                        float ssum = __expf(am - mx) + __expf(bm - mx) + s3;
                        nv = fmaf(-LAMF, mx + __logf(ssum), d);
                    }
                    vprev = val; val = nv;
                }
            }
            if (g == 17) tamv[slot] = val;
        }
    }
    __syncthreads();

    if (tid < NS) out[1 + blk * NS + tid] = 0.5f * (tamv[2 * tid] + tamv[2 * tid + 1]);
    if (tid == 0) {
        float t1v[NS], t2v[NS];
        #pragma unroll
        for (int s = 0; s < NS; ++s) { t1v[s] = tamv[2 * s]; t2v[s] = tamv[2 * s + 1]; }
        const int y = ys[blk];
        float mx1 = -t1v[0], mx2 = -t2v[0];
        #pragma unroll
        for (int s = 1; s < NS; ++s) { mx1 = fmaxf(mx1, -t1v[s]); mx2 = fmaxf(mx2, -t2v[s]); }
        float s1 = 0.f, s2 = 0.f;
        #pragma unroll
        for (int s = 0; s < NS; ++s) { s1 += __expf(-t1v[s] - mx1); s2 += __expf(-t2v[s] - mx2); }
        float lse1  = mx1 + __logf(s1);
        float lse2v = mx2 + __logf(s2);
        float ty1 = t1v[0], ty2 = t2v[0];
        #pragma unroll
        for (int s = 1; s < NS; ++s) { if (y == s) { ty1 = t1v[s]; ty2 = t2v[s]; } }
        float c = 0.5f * ((lse1 + ty1) + (lse2v + ty2));
        atomicAdd(out, c * (1.0f / (float)NROW));
    }
}

// =============================== PATH A ====================================
// One wave per row: coalesced f32 row load (32 f32/lane in regs), 64-lane
// sumsq reduce, pre-normalize (rs = 1/||row||), cvt to bf16, store in
// MFMA-FRAGMENT ORDER: element (row fr, k=kk*32+c*8+j) at tile + kk*512 +
// (c*16+fr)*8 shorts. The dist kernel then reads ONLY coalesced 1-KB
// wave-loads (8 lines/instr, the minimum) instead of 16-row scatters.
__global__ __launch_bounds__(256) void
preproc_pack(const float* __restrict__ supp, const float* __restrict__ query,
             unsigned short* __restrict__ sPk, unsigned short* __restrict__ qPk,
             float* __restrict__ loss0)
{
    if (blockIdx.x == 0 && threadIdx.x == 0) loss0[0] = 0.f;
    const int wave = threadIdx.x >> 6, lane = threadIdx.x & 63;
    const int row = blockIdx.x * 4 + wave;           // 0..17023

    const float* src;
    unsigned short* dstTile;
    int fr;
    if (row < NSROW) {
        src = supp + (size_t)row * DD;
        dstTile = sPk + (size_t)(row >> 4) * TILESH;   // tile = b*NS+s
        fr = row & 15;
    } else {
        const int qr = row - NSROW;
        src = query + (size_t)qr * DD;
        dstTile = qPk + (size_t)(qr >> 4) * TILESH;    // tile = blk
        fr = qr & 15;
    }

    // lane holds elements p = it*512 + lane*8 .. +7  (covers all 2048)
    float4 v[4][2];
    float ss = 0.f;
    #pragma unroll
    for (int it = 0; it < 4; ++it) {
        v[it][0] = *reinterpret_cast<const float4*>(src + it * 512 + lane * 8);
        v[it][1] = *reinterpret_cast<const float4*>(src + it * 512 + lane * 8 + 4);
        #pragma unroll
        for (int h = 0; h < 2; ++h)
            ss += v[it][h].x * v[it][h].x + v[it][h].y * v[it][h].y
                + v[it][h].z * v[it][h].z + v[it][h].w * v[it][h].w;
    }
    #pragma unroll
    for (int off = 32; off >= 1; off >>= 1) ss += __shfl_xor(ss, off, 64);
    const float rs = 1.0f / sqrtf(fmaxf(ss, 1e-16f));   // matches max(sn*qn,1e-8)

    #pragma unroll
    for (int it = 0; it < 4; ++it) {
        uint4 pv;
        pv.x = cvtpk(v[it][0].x * rs, v[it][0].y * rs);
        pv.y = cvtpk(v[it][0].z * rs, v[it][0].w * rs);
        pv.z = cvtpk(v[it][1].x * rs, v[it][1].y * rs);
        pv.w = cvtpk(v[it][1].z * rs, v[it][1].w * rs);
        const int kk = it * 16 + (lane >> 2);   // p/32
        const int c  = lane & 3;                // (p%32)/8
        *reinterpret_cast<uint4*>(dstTile + kk * 512 + (c * 16 + fr) * 8) = pv;
    }
}

// One block per (b,q), 4 waves, wave w owns kk = w*16..w*16+15. Per k-step:
// 1 query frag + 5 supp frags (ALL fully-coalesced 1-KB wave-loads) + 5 MFMAs.
// No cvt, no norms, no LDS staging, no barriers in the K-loop. dist = 1 - dot
// (inputs pre-normalized). Then 4-wave reduce + DTW + fused CE.
__global__ __launch_bounds__(256, 4) void
dist_dtw_pk(const unsigned short* __restrict__ sPk, const unsigned short* __restrict__ qPk,
            const int* __restrict__ ys, float* __restrict__ out)
{
    __shared__ __align__(16) float red[4][NS][64][4];  // 20 KB
    __shared__ float distS[NS][TT][TT];
    __shared__ float tamv[12];

    const int tid  = threadIdx.x;
    const int blk  = blockIdx.x;          // b*128 + q
    const int wave = tid >> 6;            // 0..3 = K-slice
    const int lane = tid & 63;

    const unsigned short* qp = qPk + (size_t)blk * TILESH + (wave * 16) * 512 + lane * 8;
    const unsigned short* sp = sPk + (size_t)(blk >> 7) * NS * TILESH
                             + (wave * 16) * 512 + lane * 8;

    float4v acc[NS];
    #pragma unroll
    for (int s = 0; s < NS; ++s) acc[s] = (float4v){0.f, 0.f, 0.f, 0.f};

    #pragma unroll 2
    for (int kk = 0; kk < 16; ++kk) {
        short8 q = *reinterpret_cast<const short8*>(qp + kk * 512);
        #pragma unroll
        for (int s = 0; s < NS; ++s) {
            short8 a = *reinterpret_cast<const short8*>(sp + (size_t)s * TILESH + kk * 512);
            acc[s] = __builtin_amdgcn_mfma_f32_16x16x32_bf16(a, q, acc[s], 0, 0, 0);
        }
    }

    #pragma unroll
    for (int s = 0; s < NS; ++s)
        *reinterpret_cast<float4v*>(red[wave][s][lane]) = acc[s];
    __syncthreads();

    // reduce 4 wave-partials; dist = 1 - dot (pre-normalized inputs)
    for (int p = tid; p < NS * 64; p += 256) {
        int t = p >> 6, ln = p & 63;
        float4v s4 = *reinterpret_cast<const float4v*>(red[0][t][ln]);
        #pragma unroll
        for (int w = 1; w < 4; ++w) {
            float4v r = *reinterpret_cast<const float4v*>(red[w][t][ln]);
            s4[0] += r[0]; s4[1] += r[1]; s4[2] += r[2]; s4[3] += r[3];
        }
        int m = ln & 15, qd = ln >> 4;
        #pragma unroll
        for (int r = 0; r < 4; ++r) distS[t][qd * 4 + r][m] = 1.0f - s4[r];
    }
    __syncthreads();

    dtw_and_out(distS, tamv, tid, blk, ys, out);
}

// =============================== PATH B (fallback, proven round-5) =========
__global__ __launch_bounds__(256) void
preproc_supp5(const float* __restrict__ supp, unsigned short* __restrict__ suppBf,
              float* __restrict__ suppSq, float* __restrict__ loss0)
{
    if (blockIdx.x == 0 && threadIdx.x == 0) loss0[0] = 0.f;
    const int wave = threadIdx.x >> 6, lane = threadIdx.x & 63;
    const int row = blockIdx.x * 4 + wave;           // 0..639
    const float* src = supp + (size_t)row * DD;
    unsigned short* dst = suppBf + (size_t)row * DD;
    float ss = 0.f;
    #pragma unroll
    for (int i = 0; i < 8; ++i) {
        float4 v = *reinterpret_cast<const float4*>(src + i * 256 + lane * 4);
        uint2 pv = { cvtpk(v.x, v.y), cvtpk(v.z, v.w) };
        *reinterpret_cast<uint2*>(dst + i * 256 + lane * 4) = pv;
        ss += v.x * v.x + v.y * v.y + v.z * v.z + v.w * v.w;
    }
    #pragma unroll
    for (int off = 32; off >= 1; off >>= 1) ss += __shfl_xor(ss, off, 64);
    if (lane == 0) suppSq[row] = ss;
}

__global__ __launch_bounds__(256, 4) void
dist_dtw_wave5(const unsigned short* __restrict__ suppBf, const float* __restrict__ suppSq,
               const float* __restrict__ query, const int* __restrict__ ys,
               float* __restrict__ out)
{
    __shared__ __align__(16) float red[4][NS][64][4];
    __shared__ float qsqp[4][16];
    __shared__ float qq[16];
    __shared__ float distS[NS][TT][TT];
    __shared__ float ssqS[80];
    __shared__ float tamv[12];

    const int tid  = threadIdx.x;
    const int blk  = blockIdx.x;
    const int wave = tid >> 6;
    const int lane = tid & 63;
    const int fr   = lane & 15;
    const int quad = lane >> 4;

    if (tid < 80) ssqS[tid] = suppSq[(blk >> 7) * (NS * TT) + tid];

    const float* qp = query + (size_t)(blk * TT + fr) * DD + wave * 512 + quad * 8;
    const unsigned short* aps[NS];
    #pragma unroll
    for (int s = 0; s < NS; ++s)
        aps[s] = suppBf + ((size_t)((blk >> 7) * NS + s) * TT + fr) * DD
               + wave * 512 + quad * 8;

    float4v acc[NS];
    #pragma unroll
    for (int s = 0; s < NS; ++s) acc[s] = (float4v){0.f, 0.f, 0.f, 0.f};
    float ss = 0.f;

    #pragma unroll 2
    for (int kk = 0; kk < 16; ++kk) {
        float4 q0 = *reinterpret_cast<const float4*>(qp + kk * 32);
        float4 q1 = *reinterpret_cast<const float4*>(qp + kk * 32 + 4);
        union { unsigned int u[4]; short8 v; } qu;
        qu.u[0] = cvtpk(q0.x, q0.y); qu.u[1] = cvtpk(q0.z, q0.w);
        qu.u[2] = cvtpk(q1.x, q1.y); qu.u[3] = cvtpk(q1.z, q1.w);
        ss += q0.x*q0.x + q0.y*q0.y + q0.z*q0.z + q0.w*q0.w
            + q1.x*q1.x + q1.y*q1.y + q1.z*q1.z + q1.w*q1.w;
        #pragma unroll
        for (int s = 0; s < NS; ++s) {
            short8 a = *reinterpret_cast<const short8*>(aps[s] + kk * 32);
            acc[s] = __builtin_amdgcn_mfma_f32_16x16x32_bf16(a, qu.v, acc[s], 0, 0, 0);
        }
    }

    ss += __shfl_xor(ss, 16, 64);
    ss += __shfl_xor(ss, 32, 64);
    if (lane < 16) qsqp[wave][lane] = ss;
    #pragma unroll
    for (int s = 0; s < NS; ++s)
        *reinterpret_cast<float4v*>(red[wave][s][lane]) = acc[s];
    __syncthreads();

    if (tid < 16) qq[tid] = qsqp[0][tid] + qsqp[1][tid] + qsqp[2][tid] + qsqp[3][tid];
    __syncthreads();

    for (int p = tid; p < NS * 64; p += 256) {
        int t = p >> 6, ln = p & 63;
        float4v s4 = *reinterpret_cast<const float4v*>(red[0][t][ln]);
        #pragma unroll
        for (int w = 1; w < 4; ++w) {
            float4v r = *reinterpret_cast<const float4v*>(red[w][t][ln]);
            s4[0] += r[0]; s4[1] += r[1]; s4[2] += r[2]; s4[3] += r[3];
        }
        int m = ln & 15, qd = ln >> 4;
        float qn = sqrtf(qq[m]);
        #pragma unroll
        for (int r = 0; r < 4; ++r) {
            int l = qd * 4 + r;
            float denom = fmaxf(sqrtf(ssqS[t * 16 + l]) * qn, 1e-8f);
            distS[t][l][m] = 1.0f - s4[r] / denom;
        }
    }
    __syncthreads();

    dtw_and_out(distS, tamv, tid, blk, ys, out);
}

extern "C" void kernel_launch(void* const* d_in, const int* in_sizes, int n_in,
                              void* d_out, int out_size, void* d_ws, size_t ws_size,
                              hipStream_t stream) {
    const float* supp  = (const float*)d_in[0];
    const float* query = (const float*)d_in[1];
    const int*   ys    = (const int*)d_in[2];
    float* out = (float*)d_out;

    const size_t needA = (size_t)(NS * NB + NROW) * TILESH * 2;   // ~66.5 MiB
    if (ws_size >= needA) {
        unsigned short* sPk = (unsigned short*)d_ws;
        unsigned short* qPk = sPk + (size_t)NS * NB * TILESH;
        preproc_pack<<<TOTROW / 4, 256, 0, stream>>>(supp, query, sPk, qPk, out);
        dist_dtw_pk<<<NROW, 256, 0, stream>>>(sPk, qPk, ys, out);
    } else {
        float* suppSq = (float*)d_ws;
        unsigned short* suppBf = (unsigned short*)(suppSq + NSROW);
        preproc_supp5<<<NSROW / 4, 256, 0, stream>>>(supp, suppBf, suppSq, out);
        dist_dtw_wave5<<<NROW, 256, 0, stream>>>(suppBf, suppSq, query, ys, out);
    }
}

// Round 7
// 225.308 us; speedup vs baseline: 1.1753x; 1.1753x over previous
//
#include <hip/hip_runtime.h>
#include <hip/hip_bf16.h>

#define NB   8
#define NS   5
#define TT   16
#define DD   2048
#define NROW 1024               // B*nq
#define NSROW 640               // supp rows
#define TILESH (TT * DD)        // 32768 shorts per packed 16x2048 tile
#define LDS_ROW 2056            // LDS row stride in shorts (+8 pad)
#define LAMI 10.0f
#define LAMF 0.1f

typedef __attribute__((ext_vector_type(8))) short  short8;
typedef __attribute__((ext_vector_type(4))) float  float4v;

// single-instruction packed f32x2 -> bf16x2 (RNE), lo = x
static __device__ __forceinline__ unsigned int cvtpk(float x, float y) {
    unsigned int r;
    asm("v_cvt_pk_bf16_f32 %0, %1, %2" : "=v"(r) : "v"(x), "v"(y));
    return r;
}

// lane i <- lane i-1 across the whole wave (lane 0 <- 0). 1 VALU op, no LDS.
static __device__ __forceinline__ float dpp_shr1(float x) {
    int r = __builtin_amdgcn_update_dpp(0, __builtin_bit_cast(int, x),
                                        0x138 /*wave_shr:1*/, 0xF, 0xF, true);
    return __builtin_bit_cast(float, r);
}

// ---- shared tail (verified R5/R6): DTW 12 lane-groups + tam + fused CE ----
static __device__ __forceinline__ void
dtw_and_out(const float (*distS)[TT][TT], float* tamv, int tid, int blk,
            const int* __restrict__ ys, float* __restrict__ out)
{
    const int wave = tid >> 6, lane = tid & 63;
    {
        const int grp  = lane / 21;             // 3 => unused tail lanes
        const int g    = lane - grp * 21;       // 0..20 within group
        const int slot = wave * 3 + grp;        // s*2+dir
        float val = 0.f, vprev = 0.f;           // init ALL lanes (dpp sources)
        if (grp < 3 && slot < 10 && g <= 17) {
            const int s    = slot >> 1;
            const int dir  = slot & 1;
            const bool isb = (g == 1) | (g == 17);
            #pragma unroll
            for (int t = 1; t <= 32; ++t) {
                float left = dpp_shr1(val);
                float diag = dpp_shr1(vprev);
                int l = t - g;
                if (g >= 1 && l >= 0 && l <= 15) {
                    float d = 0.f;
                    if (g <= 16) d = dir ? distS[s][15 - l][16 - g] : distS[s][l][g - 1];
                    float nv;
                    if (l == 0) {
                        nv = left + d;
                    } else {
                        float am = -LAMI * diag, bm = -LAMI * left;
                        float mx = fmaxf(am, bm);
                        float s3 = 0.f;
                        if (isb) {
                            float cm = -LAMI * val;
                            float m3 = fmaxf(mx, cm);
                            s3 = __expf(cm - m3);
                            mx = m3;
                        }
                        float ssum = __expf(am - mx) + __expf(bm - mx) + s3;
                        nv = fmaf(-LAMF, mx + __logf(ssum), d);
                    }
                    vprev = val; val = nv;
                }
            }
            if (g == 17) tamv[slot] = val;
        }
    }
    __syncthreads();

    if (tid < NS) out[1 + blk * NS + tid] = 0.5f * (tamv[2 * tid] + tamv[2 * tid + 1]);
    if (tid == 0) {
        float t1v[NS], t2v[NS];
        #pragma unroll
        for (int s = 0; s < NS; ++s) { t1v[s] = tamv[2 * s]; t2v[s] = tamv[2 * s + 1]; }
        const int y = ys[blk];
        float mx1 = -t1v[0], mx2 = -t2v[0];
        #pragma unroll
        for (int s = 1; s < NS; ++s) { mx1 = fmaxf(mx1, -t1v[s]); mx2 = fmaxf(mx2, -t2v[s]); }
        float s1 = 0.f, s2 = 0.f;
        #pragma unroll
        for (int s = 0; s < NS; ++s) { s1 += __expf(-t1v[s] - mx1); s2 += __expf(-t2v[s] - mx2); }
        float lse1  = mx1 + __logf(s1);
        float lse2v = mx2 + __logf(s2);
        float ty1 = t1v[0], ty2 = t2v[0];
        #pragma unroll
        for (int s = 1; s < NS; ++s) { if (y == s) { ty1 = t1v[s]; ty2 = t2v[s]; } }
        float c = 0.5f * ((lse1 + ty1) + (lse2v + ty2));
        atomicAdd(out, c * (1.0f / (float)NROW));
    }
}

// Supp-only pack (R6-verified layout + numerics). 2.6 MB of scatter-writes
// is ~2 us — negligible; the 66 MB query version of this was the R6 cost.
// One wave per row; normalize, cvt, store fragment-order:
// element (row fr, k=kk*32+c*8+j) -> tile + kk*512 + (c*16+fr)*8 + j shorts.
__global__ __launch_bounds__(256) void
pack_supp(const float* __restrict__ supp, unsigned short* __restrict__ sPk,
          float* __restrict__ loss0)
{
    if (blockIdx.x == 0 && threadIdx.x == 0) loss0[0] = 0.f;
    const int wave = threadIdx.x >> 6, lane = threadIdx.x & 63;
    const int row = blockIdx.x * 4 + wave;           // 0..639
    const float* src = supp + (size_t)row * DD;
    unsigned short* dstTile = sPk + (size_t)(row >> 4) * TILESH;   // tile = b*NS+s
    const int fr = row & 15;

    float4 v[4][2];
    float ss = 0.f;
    #pragma unroll
    for (int it = 0; it < 4; ++it) {
        v[it][0] = *reinterpret_cast<const float4*>(src + it * 512 + lane * 8);
        v[it][1] = *reinterpret_cast<const float4*>(src + it * 512 + lane * 8 + 4);
        #pragma unroll
        for (int h = 0; h < 2; ++h)
            ss += v[it][h].x * v[it][h].x + v[it][h].y * v[it][h].y
                + v[it][h].z * v[it][h].z + v[it][h].w * v[it][h].w;
    }
    #pragma unroll
    for (int off = 32; off >= 1; off >>= 1) ss += __shfl_xor(ss, off, 64);
    const float rs = 1.0f / sqrtf(fmaxf(ss, 1e-16f));

    #pragma unroll
    for (int it = 0; it < 4; ++it) {
        uint4 pv;
        pv.x = cvtpk(v[it][0].x * rs, v[it][0].y * rs);
        pv.y = cvtpk(v[it][0].z * rs, v[it][0].w * rs);
        pv.z = cvtpk(v[it][1].x * rs, v[it][1].y * rs);
        pv.w = cvtpk(v[it][1].z * rs, v[it][1].w * rs);
        const int kk = it * 16 + (lane >> 2);   // k/32
        const int c  = lane & 3;                // (k%32)/8
        *reinterpret_cast<uint4*>(dstTile + kk * 512 + (c * 16 + fr) * 8) = pv;
    }
}

// One block per (b,q), 4 waves. Phase 1: stage OWN query tile f32->normalized
// bf16 into row-major padded LDS (coalesced reads, query never round-trips
// through global as bf16). Phase 2 (barrier-free K-loop): B from LDS (R1-
// verified addressing), A from packed sPk (R6-verified coalesced 1KB wave-
// loads), 5 MFMA/k-step. Phase 3: overlay the dead 64KB tile with red/distS
// (sync-guarded), reduce, DTW, fused CE. LDS 65.8 KB -> 2 blocks/CU.
__global__ __launch_bounds__(256, 2) void
dist_dtw_fused(const unsigned short* __restrict__ sPk, const float* __restrict__ query,
               const int* __restrict__ ys, float* __restrict__ out)
{
    __shared__ __align__(16) unsigned char smem[TT * LDS_ROW * 2];   // 65792 B
    unsigned short (*sB)[LDS_ROW] = reinterpret_cast<unsigned short(*)[LDS_ROW]>(smem);
    // overlay region (valid only after the post-K-loop barrier):
    float (*red)[NS][64][4] = reinterpret_cast<float(*)[NS][64][4]>(smem);          // 20480 B
    float (*distS)[TT][TT]  = reinterpret_cast<float(*)[TT][TT]>(smem + 20480);     //  5120 B
    float* tamv             = reinterpret_cast<float*>(smem + 25600);               //    48 B

    const int tid  = threadIdx.x;
    const int blk  = blockIdx.x;          // b*128 + q
    const int wave = tid >> 6;            // 0..3
    const int lane = tid & 63;
    const int fr   = lane & 15;
    const int quad = lane >> 4;

    // ---- phase 1: stage + normalize own query tile (4 rows per wave) ----
    #pragma unroll
    for (int j = 0; j < 4; ++j) {
        const int r = wave * 4 + j;
        const float* src = query + (size_t)(blk * TT + r) * DD;
        float4 v[8];
        float ss = 0.f;
        #pragma unroll
        for (int i = 0; i < 8; ++i) {
            v[i] = *reinterpret_cast<const float4*>(src + i * 256 + lane * 4);
            ss += v[i].x * v[i].x + v[i].y * v[i].y + v[i].z * v[i].z + v[i].w * v[i].w;
        }
        #pragma unroll
        for (int off = 32; off >= 1; off >>= 1) ss += __shfl_xor(ss, off, 64);
        const float rs = 1.0f / sqrtf(fmaxf(ss, 1e-16f));
        #pragma unroll
        for (int i = 0; i < 8; ++i) {
            uint2 pv = { cvtpk(v[i].x * rs, v[i].y * rs), cvtpk(v[i].z * rs, v[i].w * rs) };
            *reinterpret_cast<uint2*>(&sB[r][i * 256 + lane * 4]) = pv;
        }
    }
    __syncthreads();

    // ---- phase 2: barrier-free K-loop; wave w owns kk = w*16 .. w*16+15 ----
    float4v acc[NS];
    #pragma unroll
    for (int s = 0; s < NS; ++s) acc[s] = (float4v){0.f, 0.f, 0.f, 0.f};

    const unsigned short* sp = sPk + (size_t)(blk >> 7) * NS * TILESH
                             + (size_t)(wave * 16) * 512 + lane * 8;
    const unsigned short* bb = &sB[fr][(wave * 16) * 32 + quad * 8];

    #pragma unroll 2
    for (int kk = 0; kk < 16; ++kk) {
        short8 b = *reinterpret_cast<const short8*>(bb + kk * 32);
        #pragma unroll
        for (int s = 0; s < NS; ++s) {
            short8 a = *reinterpret_cast<const short8*>(sp + (size_t)s * TILESH + kk * 512);
            acc[s] = __builtin_amdgcn_mfma_f32_16x16x32_bf16(a, b, acc[s], 0, 0, 0);
        }
    }
    __syncthreads();   // ALL waves done reading sB before the overlay is written

    #pragma unroll
    for (int s = 0; s < NS; ++s)
        *reinterpret_cast<float4v*>(red[wave][s][lane]) = acc[s];
    __syncthreads();

    // ---- reduce 4 wave-partials; dist = 1 - dot (pre-normalized inputs) ----
    for (int p = tid; p < NS * 64; p += 256) {
        int t = p >> 6, ln = p & 63;
        float4v s4 = *reinterpret_cast<const float4v*>(red[0][t][ln]);
        #pragma unroll
        for (int w = 1; w < 4; ++w) {
            float4v r = *reinterpret_cast<const float4v*>(red[w][t][ln]);
            s4[0] += r[0]; s4[1] += r[1]; s4[2] += r[2]; s4[3] += r[3];
        }
        int m = ln & 15, qd = ln >> 4;
        #pragma unroll
        for (int r = 0; r < 4; ++r) distS[t][qd * 4 + r][m] = 1.0f - s4[r];
    }
    __syncthreads();

    dtw_and_out(distS, tamv, tid, blk, ys, out);
}

extern "C" void kernel_launch(void* const* d_in, const int* in_sizes, int n_in,
                              void* d_out, int out_size, void* d_ws, size_t ws_size,
                              hipStream_t stream) {
    const float* supp  = (const float*)d_in[0];
    const float* query = (const float*)d_in[1];
    const int*   ys    = (const int*)d_in[2];
    float* out = (float*)d_out;

    // workspace: packed supp tiles only — 40 * 32768 shorts = 2.62 MB
    unsigned short* sPk = (unsigned short*)d_ws;

    pack_supp<<<NSROW / 4, 256, 0, stream>>>(supp, sPk, out);
    dist_dtw_fused<<<NROW, 256, 0, stream>>>(sPk, query, ys, out);
}